// Round 7
// baseline (538.691 us; speedup 1.0000x reference)
//
#include <hip/hip_runtime.h>
#include <hip/hip_cooperative_groups.h>

namespace cg = cooperative_groups;

// GCN layer: segment_sum(x@W^T)[dst] == segment_sum(x)[dst] @ W^T (linearity).
// Round-7:
//   Tier A (fast): ONE cooperative prep kernel (convert bf16, bin_count,
//     hierarchical scan, bin_scatter, bucket_sort -> exact CSR) + ONE
//     pair-interleaved bf16 gather/linear kernel.
//   Tier B: round-6 separate-kernel prep (if coop shape doesn't fit).
//   Tier C: global-atomic CSR build. Tier D: atomic scatter.

#define DIM 64
#define BN 1024           // nodes per bucket
#define BN_SHIFT 10
#define BN_MASK 1023
#define NB_MAX 128        // max buckets (LDS hist/cursor capacity)
#define PBLK 512          // prep grid blocks (coop: 2 blocks/CU)
#define PTHR 256
#define SCAN_BLOCKS 256   // tier-B scan

__device__ __forceinline__ unsigned short f32_to_bf16_rne(float f) {
    unsigned u = __float_as_uint(f);
    unsigned r = u + 0x7FFFu + ((u >> 16) & 1u);
    return (unsigned short)(r >> 16);
}

// ===========================================================================
// Tier A: fused cooperative prep kernel.
// ===========================================================================
__global__ __launch_bounds__(256) void prep_coop_kernel(
        const float* __restrict__ x, const int* __restrict__ ei,
        ushort4* __restrict__ xb4, int* __restrict__ bhistT,
        int* __restrict__ scanT, int* __restrict__ binned,
        int* __restrict__ srcs, int* __restrict__ offsets,
        int* __restrict__ bsum, int* __restrict__ bpre,
        int E, int N, int nb, int total4) {
    cg::grid_group grid = cg::this_grid();
    __shared__ int lds[2304];            // 9216 B, reused per phase
    const int t = threadIdx.x;
    const int bid = blockIdx.x;

    // ---- P0: convert x -> bf16 -------------------------------------------
    for (int i = bid * PTHR + t; i < total4; i += PBLK * PTHR) {
        float4 v = ((const float4*)x)[i];
        ushort4 o;
        o.x = f32_to_bf16_rne(v.x); o.y = f32_to_bf16_rne(v.y);
        o.z = f32_to_bf16_rne(v.z); o.w = f32_to_bf16_rne(v.w);
        xb4[i] = o;
    }

    // ---- P1: bin_count (LDS hist) -> bhistT[b*PBLK + bid] ----------------
    {
        int* h = lds;                    // [nb]
        for (int b = t; b < nb; b += PTHR) h[b] = 0;
        __syncthreads();
        for (int e = bid * PTHR + t; e < E; e += PBLK * PTHR)
            atomicAdd(&h[ei[E + e] >> BN_SHIFT], 1);
        __syncthreads();
        for (int b = t; b < nb; b += PTHR)
            bhistT[b * PBLK + bid] = h[b];
    }
    grid.sync();

    // ---- P2a: per-block chunk reduce (chunk = nb flat entries) -----------
    {
        int base = bid * nb;
        int sum = 0;
        for (int i = t; i < nb; i += PTHR) sum += bhistT[base + i];
        #pragma unroll
        for (int d = 32; d; d >>= 1) sum += __shfl_down(sum, d, 64);
        int* ws = lds;
        if ((t & 63) == 0) ws[t >> 6] = sum;
        __syncthreads();
        if (t == 0) bsum[bid] = ws[0] + ws[1] + ws[2] + ws[3];
    }
    grid.sync();

    // ---- P2b: block 0 scans the 512 partials -> bpre; total -> scanT[M] --
    if (bid == 0) {
        int* tmp = lds;                  // [256]
        int v0 = bsum[2 * t], v1 = bsum[2 * t + 1];
        int s = v0 + v1;
        tmp[t] = s;
        __syncthreads();
        #pragma unroll
        for (int d = 1; d < 256; d <<= 1) {
            int u = (t >= d) ? tmp[t - d] : 0;
            __syncthreads();
            tmp[t] += u;
            __syncthreads();
        }
        int excl = tmp[t] - s;
        bpre[2 * t]     = excl;
        bpre[2 * t + 1] = excl + v0;
        if (t == 255) scanT[nb * PBLK] = tmp[255];   // = E
    }
    grid.sync();

    // ---- P2c: each block scans its nb-entry chunk ------------------------
    {
        int* tmp = lds;                  // [128]
        int base = bid * nb;
        int v = (t < nb) ? bhistT[base + t] : 0;
        if (t < 128) tmp[t] = v;
        __syncthreads();
        #pragma unroll
        for (int d = 1; d < 128; d <<= 1) {
            int u = 0;
            if (t < 128 && t >= d) u = tmp[t - d];
            __syncthreads();
            if (t < 128) tmp[t] += u;
            __syncthreads();
        }
        if (t < nb) scanT[base + t] = bpre[bid] + tmp[t] - v;
    }
    grid.sync();

    // ---- P3: bin_scatter (LDS cursors) -----------------------------------
    {
        int* cur = lds;                  // [nb]
        for (int b = t; b < nb; b += PTHR) cur[b] = scanT[b * PBLK + bid];
        __syncthreads();
        for (int e = bid * PTHR + t; e < E; e += PBLK * PTHR) {
            int s = ei[e];
            int d = ei[E + e];
            int p = atomicAdd(&cur[d >> BN_SHIFT], 1);
            binned[p] = (s << BN_SHIFT) | (d & BN_MASK);
        }
    }
    grid.sync();

    // ---- P4: bucket_sort (blocks bid < nb) -> exact CSR ------------------
    if (bid < nb) {
        int* cnt   = lds;                // [1024]
        int* basep = lds + 1024;         // [1024]
        int* tsum  = lds + 2048;         // [256]
        const int seg0 = scanT[bid * PBLK];
        const int seg1 = scanT[(bid + 1) * PBLK];
        for (int j = t; j < BN; j += PTHR) cnt[j] = 0;
        __syncthreads();
        for (int i = seg0 + t; i < seg1; i += PTHR)
            atomicAdd(&cnt[binned[i] & BN_MASK], 1);
        __syncthreads();
        int c0 = cnt[4 * t + 0], c1 = cnt[4 * t + 1];
        int c2 = cnt[4 * t + 2], c3 = cnt[4 * t + 3];
        int s4 = c0 + c1 + c2 + c3;
        tsum[t] = s4;
        __syncthreads();
        #pragma unroll
        for (int d = 1; d < 256; d <<= 1) {
            int u = (t >= d) ? tsum[t - d] : 0;
            __syncthreads();
            tsum[t] += u;
            __syncthreads();
        }
        int excl = tsum[t] - s4;
        basep[4 * t + 0] = excl;
        basep[4 * t + 1] = excl + c0;
        basep[4 * t + 2] = excl + c0 + c1;
        basep[4 * t + 3] = excl + c0 + c1 + c2;
        __syncthreads();
        const int node0 = bid << BN_SHIFT;
        for (int j = t; j < BN; j += PTHR)
            if (node0 + j < N) offsets[node0 + j] = seg0 + basep[j];
        if (bid == 0 && t == 0) offsets[N] = scanT[nb * PBLK];
        for (int j = t; j < BN; j += PTHR) cnt[j] = basep[j];   // cursors
        __syncthreads();
        for (int i = seg0 + t; i < seg1; i += PTHR) {
            int v = binned[i];
            int p = atomicAdd(&cnt[v & BN_MASK], 1);
            srcs[seg0 + p] = v >> BN_SHIFT;
        }
    }
}

// ===========================================================================
// Gather/linear: pair-interleaved bf16; 8 lanes/edge x 16B dwordx4.
// ===========================================================================
__device__ __forceinline__ void acc8(float (&a)[8], const uint4& v) {
    a[0] += __uint_as_float(v.x << 16); a[1] += __uint_as_float(v.x & 0xFFFF0000u);
    a[2] += __uint_as_float(v.y << 16); a[3] += __uint_as_float(v.y & 0xFFFF0000u);
    a[4] += __uint_as_float(v.z << 16); a[5] += __uint_as_float(v.z & 0xFFFF0000u);
    a[6] += __uint_as_float(v.w << 16); a[7] += __uint_as_float(v.w & 0xFFFF0000u);
}

__device__ __forceinline__ float epilogue64(const float (&a)[8],
                                            const float (&wv)[DIM], float bb) {
    float r0 = bb, r1 = 0.f, r2 = 0.f, r3 = 0.f;
    #pragma unroll
    for (int k = 0; k < DIM; k += 4) {
        r0 += __int_as_float(__builtin_amdgcn_readlane(
                  __float_as_int(a[(k + 0) & 7]), (k + 0) >> 3)) * wv[k + 0];
        r1 += __int_as_float(__builtin_amdgcn_readlane(
                  __float_as_int(a[(k + 1) & 7]), (k + 1) >> 3)) * wv[k + 1];
        r2 += __int_as_float(__builtin_amdgcn_readlane(
                  __float_as_int(a[(k + 2) & 7]), (k + 2) >> 3)) * wv[k + 2];
        r3 += __int_as_float(__builtin_amdgcn_readlane(
                  __float_as_int(a[(k + 3) & 7]), (k + 3) >> 3)) * wv[k + 3];
    }
    return (r0 + r1) + (r2 + r3);
}

__global__ __launch_bounds__(256) void gather_linear_bf16_pair_kernel(
        const unsigned short* __restrict__ xh, const int* __restrict__ offsets,
        const int* __restrict__ srcs, const float* __restrict__ W,
        const float* __restrict__ bias, float* __restrict__ out,
        int n_nodes, int half) {
    const int lane = threadIdx.x & 63;
    const int sub  = lane >> 3;          // edge slot 0..7
    const int fb   = (lane & 7) << 3;    // feature base
    const int gwave = (blockIdx.x * blockDim.x + threadIdx.x) >> 6;
    const int total_waves = (gridDim.x * blockDim.x) >> 6;

    float wv[DIM];
    #pragma unroll
    for (int k4 = 0; k4 < DIM / 4; ++k4) {
        float4 tw = *(const float4*)(W + (size_t)lane * DIM + k4 * 4);
        wv[k4 * 4 + 0] = tw.x; wv[k4 * 4 + 1] = tw.y;
        wv[k4 * 4 + 2] = tw.z; wv[k4 * 4 + 3] = tw.w;
    }
    const float bb = bias[lane];

    for (int nA = gwave; nA < half; nA += total_waves) {
        const int nB = nA + half;
        int iA = offsets[nA], endA = offsets[nA + 1];
        int iB = 0, endB = 0;
        if (nB < n_nodes) { iB = offsets[nB]; endB = offsets[nB + 1]; }

        float a[8] = {0.f, 0.f, 0.f, 0.f, 0.f, 0.f, 0.f, 0.f};
        float c[8] = {0.f, 0.f, 0.f, 0.f, 0.f, 0.f, 0.f, 0.f};
        while (iA < endA || iB < endB) {       // wave-uniform condition
            uint4 vA, vB;
            bool mA = false, mB = false;
            if (iA < endA) {
                int idx = iA + sub;
                if (idx < endA) {
                    vA = *(const uint4*)(xh + (size_t)srcs[idx] * DIM + fb);
                    mA = true;
                }
                iA += 8;
            }
            if (iB < endB) {
                int idx = iB + sub;
                if (idx < endB) {
                    vB = *(const uint4*)(xh + (size_t)srcs[idx] * DIM + fb);
                    mB = true;
                }
                iB += 8;
            }
            if (mA) acc8(a, vA);
            if (mB) acc8(c, vB);
        }

        #pragma unroll
        for (int d = 8; d <= 32; d <<= 1) {
            #pragma unroll
            for (int j = 0; j < 8; ++j) {
                a[j] += __shfl_xor(a[j], d, 64);
                c[j] += __shfl_xor(c[j], d, 64);
            }
        }

        out[(size_t)nA * DIM + lane] = epilogue64(a, wv, bb);
        if (nB < n_nodes)
            out[(size_t)nB * DIM + lane] = epilogue64(c, wv, bb);
    }
}

// ===========================================================================
// Tier B: round-6 separate-kernel prep (fallback if coop shape unavailable).
// ===========================================================================
__global__ void convert_bf16_kernel(const float* __restrict__ x,
                                    ushort4* __restrict__ xb4, int total4) {
    int i = blockIdx.x * blockDim.x + threadIdx.x;
    if (i >= total4) return;
    float4 v = ((const float4*)x)[i];
    ushort4 o;
    o.x = f32_to_bf16_rne(v.x); o.y = f32_to_bf16_rne(v.y);
    o.z = f32_to_bf16_rne(v.z); o.w = f32_to_bf16_rne(v.w);
    xb4[i] = o;
}

__global__ __launch_bounds__(256) void bin_count_kernel(
        const int* __restrict__ ei, int* __restrict__ bhistT, int E, int nb) {
    __shared__ int h[NB_MAX];
    int t = threadIdx.x;
    for (int b = t; b < nb; b += 256) h[b] = 0;
    __syncthreads();
    for (int e = blockIdx.x * 256 + t; e < E; e += PBLK * 256)
        atomicAdd(&h[ei[E + e] >> BN_SHIFT], 1);
    __syncthreads();
    for (int b = t; b < nb; b += 256)
        bhistT[b * PBLK + blockIdx.x] = h[b];
}

__global__ void scan_reduce_kernel(const int* __restrict__ in,
                                   int* __restrict__ bsum, int n, int chunk) {
    __shared__ int ws[4];
    int b = blockIdx.x, t = threadIdx.x;
    int base = b * chunk;
    int lim = min(base + chunk, n);
    int sum = 0;
    for (int i = base + t; i < lim; i += 256) sum += in[i];
    #pragma unroll
    for (int d = 32; d; d >>= 1) sum += __shfl_down(sum, d, 64);
    if ((t & 63) == 0) ws[t >> 6] = sum;
    __syncthreads();
    if (t == 0) bsum[b] = ws[0] + ws[1] + ws[2] + ws[3];
}

__global__ void scan_partials_kernel(const int* __restrict__ bsum,
                                     int* __restrict__ bpre,
                                     int* __restrict__ outp, int n) {
    __shared__ int tmp[SCAN_BLOCKS];
    int t = threadIdx.x;
    int v = bsum[t];
    tmp[t] = v;
    __syncthreads();
    #pragma unroll
    for (int d = 1; d < SCAN_BLOCKS; d <<= 1) {
        int u = (t >= d) ? tmp[t - d] : 0;
        __syncthreads();
        tmp[t] += u;
        __syncthreads();
    }
    bpre[t] = tmp[t] - v;
    if (t == SCAN_BLOCKS - 1) outp[n] = tmp[t];
}

__global__ void scan_write_kernel(const int* __restrict__ in,
                                  const int* __restrict__ bpre,
                                  int* __restrict__ outp, int n, int chunk) {
    __shared__ int tmp[256];
    int b = blockIdx.x, t = threadIdx.x;
    int base = b * chunk;
    int lim = min(base + chunk, n);
    int carry = bpre[b];
    for (int tile = base; tile < lim; tile += 256) {
        int i = tile + t;
        int v = (i < lim) ? in[i] : 0;
        tmp[t] = v;
        __syncthreads();
        #pragma unroll
        for (int d = 1; d < 256; d <<= 1) {
            int u = (t >= d) ? tmp[t - d] : 0;
            __syncthreads();
            tmp[t] += u;
            __syncthreads();
        }
        if (i < lim) outp[i] = carry + (tmp[t] - v);
        int total = tmp[255];
        __syncthreads();
        carry += total;
    }
}

__global__ __launch_bounds__(256) void bin_scatter_kernel(
        const int* __restrict__ ei, const int* __restrict__ scanT,
        int* __restrict__ binned, int E, int nb) {
    __shared__ int cur[NB_MAX];
    int t = threadIdx.x;
    for (int b = t; b < nb; b += 256) cur[b] = scanT[b * PBLK + blockIdx.x];
    __syncthreads();
    for (int e = blockIdx.x * 256 + t; e < E; e += PBLK * 256) {
        int s = ei[e];
        int d = ei[E + e];
        int p = atomicAdd(&cur[d >> BN_SHIFT], 1);
        binned[p] = (s << BN_SHIFT) | (d & BN_MASK);
    }
}

__global__ __launch_bounds__(256) void bucket_sort_kernel(
        const int* __restrict__ binned, const int* __restrict__ scanT,
        int* __restrict__ srcs, int* __restrict__ offsets, int N, int nb) {
    __shared__ int cnt[BN];
    __shared__ int basep[BN];
    __shared__ int tsum[256];
    const int t = threadIdx.x;
    const int b = blockIdx.x;
    const int seg0 = scanT[b * PBLK];
    const int seg1 = scanT[(b + 1) * PBLK];
    for (int j = t; j < BN; j += 256) cnt[j] = 0;
    __syncthreads();
    for (int i = seg0 + t; i < seg1; i += 256)
        atomicAdd(&cnt[binned[i] & BN_MASK], 1);
    __syncthreads();
    int c0 = cnt[4 * t + 0], c1 = cnt[4 * t + 1];
    int c2 = cnt[4 * t + 2], c3 = cnt[4 * t + 3];
    int s4 = c0 + c1 + c2 + c3;
    tsum[t] = s4;
    __syncthreads();
    #pragma unroll
    for (int d = 1; d < 256; d <<= 1) {
        int u = (t >= d) ? tsum[t - d] : 0;
        __syncthreads();
        tsum[t] += u;
        __syncthreads();
    }
    int excl = tsum[t] - s4;
    basep[4 * t + 0] = excl;
    basep[4 * t + 1] = excl + c0;
    basep[4 * t + 2] = excl + c0 + c1;
    basep[4 * t + 3] = excl + c0 + c1 + c2;
    __syncthreads();
    const int node0 = b << BN_SHIFT;
    for (int j = t; j < BN; j += 256)
        if (node0 + j < N) offsets[node0 + j] = seg0 + basep[j];
    if (b == 0 && t == 0) offsets[N] = scanT[(size_t)nb * PBLK];
    for (int j = t; j < BN; j += 256) cnt[j] = basep[j];
    __syncthreads();
    for (int i = seg0 + t; i < seg1; i += 256) {
        int v = binned[i];
        int p = atomicAdd(&cnt[v & BN_MASK], 1);
        srcs[seg0 + p] = v >> BN_SHIFT;
    }
}

// ------------------- tier C: global-atomic CSR build -----------------------
__global__ void hist_kernel(const int* __restrict__ ei, int* __restrict__ counts,
                            int E) {
    int e = blockIdx.x * blockDim.x + threadIdx.x;
    if (e < E) atomicAdd(&counts[ei[E + e]], 1);
}

__global__ void copy_kernel(const int* __restrict__ src, int* __restrict__ dst,
                            int n) {
    int i = blockIdx.x * blockDim.x + threadIdx.x;
    if (i < n) dst[i] = src[i];
}

__global__ void fill_kernel(const int* __restrict__ ei, int* __restrict__ cursor,
                            int* __restrict__ srcs, int E) {
    int e = blockIdx.x * blockDim.x + threadIdx.x;
    if (e < E) {
        int d = ei[E + e];
        int p = atomicAdd(&cursor[d], 1);
        srcs[p] = ei[e];
    }
}

__global__ __launch_bounds__(256) void gather_linear_f32_kernel(
        const float* __restrict__ xf, const int* __restrict__ offsets,
        const int* __restrict__ srcs, const float* __restrict__ W,
        const float* __restrict__ bias, float* __restrict__ out, int n_nodes) {
    const int lane = threadIdx.x & 63;
    const int gwave = (blockIdx.x * blockDim.x + threadIdx.x) >> 6;
    const int total_waves = (gridDim.x * blockDim.x) >> 6;
    float wv[DIM];
    #pragma unroll
    for (int k4 = 0; k4 < DIM / 4; ++k4) {
        float4 tw = *(const float4*)(W + (size_t)lane * DIM + k4 * 4);
        wv[k4 * 4 + 0] = tw.x; wv[k4 * 4 + 1] = tw.y;
        wv[k4 * 4 + 2] = tw.z; wv[k4 * 4 + 3] = tw.w;
    }
    const float b = bias[lane];
    for (int node = gwave; node < n_nodes; node += total_waves) {
        int beg = offsets[node];
        int end = offsets[node + 1];
        float a0 = 0.f, a1 = 0.f, a2 = 0.f, a3 = 0.f;
        int i = beg;
        for (; i + 4 <= end; i += 4) {
            int s0 = srcs[i + 0], s1 = srcs[i + 1];
            int s2 = srcs[i + 2], s3 = srcs[i + 3];
            a0 += xf[(size_t)s0 * DIM + lane];
            a1 += xf[(size_t)s1 * DIM + lane];
            a2 += xf[(size_t)s2 * DIM + lane];
            a3 += xf[(size_t)s3 * DIM + lane];
        }
        for (; i < end; ++i) a0 += xf[(size_t)srcs[i] * DIM + lane];
        float acc = (a0 + a1) + (a2 + a3);
        float r0 = b, r1 = 0.f, r2 = 0.f, r3 = 0.f;
        #pragma unroll
        for (int k = 0; k < DIM; k += 4) {
            r0 += __int_as_float(__builtin_amdgcn_readlane(__float_as_int(acc), k + 0)) * wv[k + 0];
            r1 += __int_as_float(__builtin_amdgcn_readlane(__float_as_int(acc), k + 1)) * wv[k + 1];
            r2 += __int_as_float(__builtin_amdgcn_readlane(__float_as_int(acc), k + 2)) * wv[k + 2];
            r3 += __int_as_float(__builtin_amdgcn_readlane(__float_as_int(acc), k + 3)) * wv[k + 3];
        }
        out[(size_t)node * DIM + lane] = (r0 + r1) + (r2 + r3);
    }
}

// ------------------- tier D: atomic scatter fallback -----------------------
__global__ void gcn_scatter_kernel(const float* __restrict__ x,
                                   const int* __restrict__ edge_index,
                                   float* __restrict__ out, int n_edges) {
    int gid = blockIdx.x * blockDim.x + threadIdx.x;
    int e = gid >> 4;
    if (e >= n_edges) return;
    int j = (gid & 15) << 2;
    int src = edge_index[e];
    int dst = edge_index[n_edges + e];
    const float4 v = *(const float4*)(x + (size_t)src * DIM + j);
    float* o = out + (size_t)dst * DIM + j;
    atomicAdd(o + 0, v.x); atomicAdd(o + 1, v.y);
    atomicAdd(o + 2, v.z); atomicAdd(o + 3, v.w);
}

__global__ void gcn_linear_inplace_kernel(float* __restrict__ out,
                                          const float* __restrict__ W,
                                          const float* __restrict__ bias,
                                          int n_nodes) {
    __shared__ float Wt[DIM * DIM];
    __shared__ float rows[4][DIM];
    int tid = threadIdx.x;
    int col = tid & 63;
    int r = tid >> 6;
    for (int i = tid; i < DIM * DIM; i += 256) {
        int c = i >> 6, k = i & 63;
        Wt[k * DIM + c] = W[i];
    }
    int row = blockIdx.x * 4 + r;
    if (row < n_nodes) rows[r][col] = out[(size_t)row * DIM + col];
    __syncthreads();
    if (row < n_nodes) {
        float a = 0.f;
        #pragma unroll
        for (int k = 0; k < DIM; ++k) a += rows[r][k] * Wt[k * DIM + col];
        out[(size_t)row * DIM + col] = a + bias[col];
    }
}

// ===========================================================================
extern "C" void kernel_launch(void* const* d_in, const int* in_sizes, int n_in,
                              void* d_out, int out_size, void* d_ws, size_t ws_size,
                              hipStream_t stream) {
    const float* x          = (const float*)d_in[0];   // [N, 64]
    const float* W          = (const float*)d_in[1];   // [64, 64]
    const float* bias       = (const float*)d_in[2];   // [64]
    const int*   edge_index = (const int*)d_in[3];     // [2, E]

    int E = in_sizes[3] / 2;
    int N = in_sizes[0] / DIM;
    float* out = (float*)d_out;

    int nb = (N + BN - 1) >> BN_SHIFT;
    const long long M = (long long)nb * PBLK;
    const int block = 256;

    auto align256 = [](size_t v) { return (v + 255) & ~(size_t)255; };
    const size_t xb_b   = align256((size_t)N * DIM * 2);
    const size_t bin_b  = align256((size_t)E * 4);
    const size_t hist_b = align256((size_t)M * 4);
    const size_t scan_b = align256(((size_t)M + 1) * 4);
    const size_t srcs_b = align256((size_t)E * 4);
    const size_t offs_b = align256(((size_t)N + 1) * 4);
    const size_t sm_b   = align256((size_t)PBLK * 4);
    const size_t needA = xb_b + bin_b + hist_b + scan_b + srcs_b + offs_b + 2 * sm_b;
    const size_t needC = ((size_t)3 * N + 1 + E + 2 * SCAN_BLOCKS) * sizeof(int);

    if (nb <= NB_MAX && (N & 3) == 0 && ws_size >= needA) {
        char* p = (char*)d_ws;
        ushort4* xb4 = (ushort4*)p;          p += xb_b;
        int* binned  = (int*)p;              p += bin_b;
        int* bhistT  = (int*)p;              p += hist_b;
        int* scanT   = (int*)p;              p += scan_b;
        int* srcs    = (int*)p;              p += srcs_b;
        int* offsets = (int*)p;              p += offs_b;
        int* bsum    = (int*)p;              p += sm_b;
        int* bpre    = (int*)p;

        int total4 = N * DIM / 4;
        void* args[] = {(void*)&x, (void*)&edge_index, (void*)&xb4,
                        (void*)&bhistT, (void*)&scanT, (void*)&binned,
                        (void*)&srcs, (void*)&offsets, (void*)&bsum,
                        (void*)&bpre, (void*)&E, (void*)&N, (void*)&nb,
                        (void*)&total4};
        hipError_t err = hipLaunchCooperativeKernel(
            (const void*)prep_coop_kernel, dim3(PBLK), dim3(PTHR),
            args, 0, stream);

        if (err != hipSuccess) {
            // Tier B: separate-kernel prep (same ws layout)
            const int chunkM = (int)((M + SCAN_BLOCKS - 1) / SCAN_BLOCKS);
            convert_bf16_kernel<<<(total4 + block - 1) / block, block, 0, stream>>>(
                x, xb4, total4);
            bin_count_kernel<<<PBLK, block, 0, stream>>>(edge_index, bhistT, E, nb);
            scan_reduce_kernel<<<SCAN_BLOCKS, block, 0, stream>>>(bhistT, bsum, (int)M, chunkM);
            scan_partials_kernel<<<1, SCAN_BLOCKS, 0, stream>>>(bsum, bpre, scanT, (int)M);
            scan_write_kernel<<<SCAN_BLOCKS, block, 0, stream>>>(bhistT, bpre, scanT, (int)M, chunkM);
            bin_scatter_kernel<<<PBLK, block, 0, stream>>>(edge_index, scanT, binned, E, nb);
            bucket_sort_kernel<<<nb, block, 0, stream>>>(binned, scanT, srcs, offsets, N, nb);
        }

        int half = (N + 1) / 2;
        int waves = (half + 3) / 4;              // ~4 pairs per wave
        int ggrid = (waves + 3) / 4;
        gather_linear_bf16_pair_kernel<<<ggrid, block, 0, stream>>>(
            (const unsigned short*)xb4, offsets, srcs, W, bias, out, N, half);
    } else if (ws_size >= needC) {
        int* counts  = (int*)d_ws;
        int* offsets = counts + N;
        int* cursor  = offsets + N + 1;
        int* srcs    = cursor + N;
        int* bsum    = srcs + E;
        int* bpre    = bsum + SCAN_BLOCKS;

        hipMemsetAsync(counts, 0, (size_t)N * sizeof(int), stream);
        const int egrid = (E + block - 1) / block;
        const int chunkN = (N + SCAN_BLOCKS - 1) / SCAN_BLOCKS;
        hist_kernel<<<egrid, block, 0, stream>>>(edge_index, counts, E);
        scan_reduce_kernel<<<SCAN_BLOCKS, block, 0, stream>>>(counts, bsum, N, chunkN);
        scan_partials_kernel<<<1, SCAN_BLOCKS, 0, stream>>>(bsum, bpre, offsets, N);
        scan_write_kernel<<<SCAN_BLOCKS, block, 0, stream>>>(counts, bpre, offsets, N, chunkN);
        copy_kernel<<<(N + block - 1) / block, block, 0, stream>>>(offsets, cursor, N);
        fill_kernel<<<egrid, block, 0, stream>>>(edge_index, cursor, srcs, E);
        int waves = (N + 7) / 8;
        int ggrid = (waves + 3) / 4;
        gather_linear_f32_kernel<<<ggrid, block, 0, stream>>>(
            x, offsets, srcs, W, bias, out, N);
    } else {
        hipMemsetAsync(d_out, 0, (size_t)out_size * sizeof(float), stream);
        long long total = (long long)E * 16;
        int grid = (int)((total + block - 1) / block);
        gcn_scatter_kernel<<<grid, block, 0, stream>>>(x, edge_index, out, E);
        int lgrid = (N + 3) / 4;
        gcn_linear_inplace_kernel<<<lgrid, 256, 0, stream>>>(out, W, bias, N);
    }
}

// Round 8
// 234.382 us; speedup vs baseline: 2.2983x; 2.2983x over previous
//
#include <hip/hip_runtime.h>

// GCN layer: segment_sum(x@W^T)[dst] == segment_sum(x)[dst] @ W^T (linearity).
// Round-8 pipeline (5 dispatches, zero global atomics, no grid.sync):
//   K1 convert+bin_count : x->bf16 (+zero row N), LDS hist -> bhistT[b*512+blk]
//   K2 scan_all          : one kernel; each of nb blocks reads all bhistT,
//                          computes bucket bases + its column scan -> scanT
//   K3 bin_scatter       : LDS cursors; binned[p] = (src<<10)|(dst&1023)
//   K4 bucket_sort       : block/bucket; 1024 LDS counters -> exact CSR
//   K5 gather_quad       : wave per 4 nodes, BRANCHLESS chunk loop:
//                          4 row-loads (dwordx4 bf16) in flight; invalid
//                          chunks redirect to zero row (cndmask, no branches);
//                          shfl_xor reduce + readlane @ W^T epilogue.
// Tier D fallback (tiny ws): atomic scatter + LDS linear.

#define DIM 64
#define BN 1024
#define BN_SHIFT 10
#define BN_MASK 1023
#define NB_MAX 128
#define PBLK 512

__device__ __forceinline__ unsigned short f32_to_bf16_rne(float f) {
    unsigned u = __float_as_uint(f);
    unsigned r = u + 0x7FFFu + ((u >> 16) & 1u);
    return (unsigned short)(r >> 16);
}

// ---------------------------------------------------------------------------
// K1: convert x -> bf16 (incl. zero row N) + per-block LDS histogram.
__global__ __launch_bounds__(256) void convert_hist_kernel(
        const float* __restrict__ x, const int* __restrict__ ei,
        ushort4* __restrict__ xb4, int* __restrict__ bhistT,
        int E, int N, int nb, int total4) {
    __shared__ int h[NB_MAX];
    const int t = threadIdx.x;
    const int bid = blockIdx.x;

    for (int b = t; b < nb; b += 256) h[b] = 0;

    // convert (no sync needed vs hist: independent data)
    for (int i = bid * 256 + t; i < total4; i += PBLK * 256) {
        float4 v = ((const float4*)x)[i];
        ushort4 o;
        o.x = f32_to_bf16_rne(v.x); o.y = f32_to_bf16_rne(v.y);
        o.z = f32_to_bf16_rne(v.z); o.w = f32_to_bf16_rne(v.w);
        xb4[i] = o;
    }
    // zero row N (gather's dummy target)
    if (bid == 0 && t < 16) {
        ushort4 z; z.x = 0; z.y = 0; z.z = 0; z.w = 0;
        xb4[(size_t)N * 16 + t] = z;
    }
    __syncthreads();

    for (int e = bid * 256 + t; e < E; e += PBLK * 256)
        atomicAdd(&h[ei[E + e] >> BN_SHIFT], 1);
    __syncthreads();
    for (int b = t; b < nb; b += 256)
        bhistT[b * PBLK + bid] = h[b];
}

// ---------------------------------------------------------------------------
// K2: one-dispatch scan. Block b: (a) every block redundantly computes all
// bucket totals from bhistT (L2-hot, ~200KB), (b) serial exclusive scan of
// nb totals, (c) scans its own 512-entry column -> scanT[b*512+blk].
__global__ __launch_bounds__(256) void scan_all_kernel(
        const int* __restrict__ bhistT, int* __restrict__ scanT, int nb) {
    __shared__ int tot[NB_MAX];
    __shared__ int tmp[256];
    const int t = threadIdx.x;
    const int b = blockIdx.x;

    if (t < nb) {
        const int4* p4 = (const int4*)(bhistT + (size_t)t * PBLK);
        int s = 0;
        #pragma unroll 8
        for (int k = 0; k < PBLK / 4; ++k) {
            int4 v = p4[k];
            s += v.x + v.y + v.z + v.w;
        }
        tot[t] = s;
    }
    __syncthreads();
    if (t == 0) {
        int run = 0;
        for (int j = 0; j < nb; ++j) { int v = tot[j]; tot[j] = run; run += v; }
        if (b == 0) scanT[(size_t)nb * PBLK] = run;   // = E
    }
    __syncthreads();

    // column scan: 512 entries, 2 per thread
    int v0 = bhistT[b * PBLK + 2 * t];
    int v1 = bhistT[b * PBLK + 2 * t + 1];
    int s2 = v0 + v1;
    tmp[t] = s2;
    __syncthreads();
    #pragma unroll
    for (int d = 1; d < 256; d <<= 1) {
        int u = (t >= d) ? tmp[t - d] : 0;
        __syncthreads();
        tmp[t] += u;
        __syncthreads();
    }
    int excl = tmp[t] - s2;
    const int base = tot[b];
    scanT[b * PBLK + 2 * t]     = base + excl;
    scanT[b * PBLK + 2 * t + 1] = base + excl + v0;
}

// ---------------------------------------------------------------------------
// K3: bin_scatter (LDS cursors).
__global__ __launch_bounds__(256) void bin_scatter_kernel(
        const int* __restrict__ ei, const int* __restrict__ scanT,
        int* __restrict__ binned, int E, int nb) {
    __shared__ int cur[NB_MAX];
    int t = threadIdx.x;
    for (int b = t; b < nb; b += 256) cur[b] = scanT[b * PBLK + blockIdx.x];
    __syncthreads();
    for (int e = blockIdx.x * 256 + t; e < E; e += PBLK * 256) {
        int s = ei[e];
        int d = ei[E + e];
        int p = atomicAdd(&cur[d >> BN_SHIFT], 1);
        binned[p] = (s << BN_SHIFT) | (d & BN_MASK);
    }
}

// ---------------------------------------------------------------------------
// K4: bucket_sort -> exact CSR (offsets, srcs). Same as round 6 (proven).
__global__ __launch_bounds__(256) void bucket_sort_kernel(
        const int* __restrict__ binned, const int* __restrict__ scanT,
        int* __restrict__ srcs, int* __restrict__ offsets, int N, int nb) {
    __shared__ int cnt[BN];
    __shared__ int basep[BN];
    __shared__ int tsum[256];
    const int t = threadIdx.x;
    const int b = blockIdx.x;
    const int seg0 = scanT[b * PBLK];
    const int seg1 = scanT[(b + 1) * PBLK];   // b=nb-1 -> scanT[nb*PBLK]=E
    for (int j = t; j < BN; j += 256) cnt[j] = 0;
    __syncthreads();
    for (int i = seg0 + t; i < seg1; i += 256)
        atomicAdd(&cnt[binned[i] & BN_MASK], 1);
    __syncthreads();
    int c0 = cnt[4 * t + 0], c1 = cnt[4 * t + 1];
    int c2 = cnt[4 * t + 2], c3 = cnt[4 * t + 3];
    int s4 = c0 + c1 + c2 + c3;
    tsum[t] = s4;
    __syncthreads();
    #pragma unroll
    for (int d = 1; d < 256; d <<= 1) {
        int u = (t >= d) ? tsum[t - d] : 0;
        __syncthreads();
        tsum[t] += u;
        __syncthreads();
    }
    int excl = tsum[t] - s4;
    basep[4 * t + 0] = excl;
    basep[4 * t + 1] = excl + c0;
    basep[4 * t + 2] = excl + c0 + c1;
    basep[4 * t + 3] = excl + c0 + c1 + c2;
    __syncthreads();
    const int node0 = b << BN_SHIFT;
    for (int j = t; j < BN; j += 256)
        if (node0 + j < N) offsets[node0 + j] = seg0 + basep[j];
    if (b == 0 && t == 0) offsets[N] = scanT[(size_t)nb * PBLK];
    for (int j = t; j < BN; j += 256) cnt[j] = basep[j];   // cursors
    __syncthreads();
    for (int i = seg0 + t; i < seg1; i += 256) {
        int v = binned[i];
        int p = atomicAdd(&cnt[v & BN_MASK], 1);
        srcs[seg0 + p] = v >> BN_SHIFT;
    }
}

// ---------------------------------------------------------------------------
// K5: branchless quad-node gather. 8 lanes/edge x 16B dwordx4; invalid chunk
// slots select the zero row (index N) via cndmask -> no branches, no tails.
__device__ __forceinline__ void acc8(float (&a)[8], const uint4& v) {
    a[0] += __uint_as_float(v.x << 16); a[1] += __uint_as_float(v.x & 0xFFFF0000u);
    a[2] += __uint_as_float(v.y << 16); a[3] += __uint_as_float(v.y & 0xFFFF0000u);
    a[4] += __uint_as_float(v.z << 16); a[5] += __uint_as_float(v.z & 0xFFFF0000u);
    a[6] += __uint_as_float(v.w << 16); a[7] += __uint_as_float(v.w & 0xFFFF0000u);
}

__device__ __forceinline__ float epilogue64(const float (&a)[8],
                                            const float (&wv)[DIM], float bb) {
    float r0 = bb, r1 = 0.f, r2 = 0.f, r3 = 0.f;
    #pragma unroll
    for (int k = 0; k < DIM; k += 4) {
        r0 += __int_as_float(__builtin_amdgcn_readlane(
                  __float_as_int(a[(k + 0) & 7]), (k + 0) >> 3)) * wv[k + 0];
        r1 += __int_as_float(__builtin_amdgcn_readlane(
                  __float_as_int(a[(k + 1) & 7]), (k + 1) >> 3)) * wv[k + 1];
        r2 += __int_as_float(__builtin_amdgcn_readlane(
                  __float_as_int(a[(k + 2) & 7]), (k + 2) >> 3)) * wv[k + 2];
        r3 += __int_as_float(__builtin_amdgcn_readlane(
                  __float_as_int(a[(k + 3) & 7]), (k + 3) >> 3)) * wv[k + 3];
    }
    return (r0 + r1) + (r2 + r3);
}

__global__ __launch_bounds__(256) void gather_quad_kernel(
        const unsigned short* __restrict__ xh, const int* __restrict__ offsets,
        const int* __restrict__ srcs, const float* __restrict__ W,
        const float* __restrict__ bias, float* __restrict__ out,
        int n_nodes, int E) {
    const int lane = threadIdx.x & 63;
    const int sub  = lane >> 3;          // edge slot 0..7
    const int fb   = (lane & 7) << 3;    // feature base
    const int gwave = (blockIdx.x * blockDim.x + threadIdx.x) >> 6;
    const int total_waves = (gridDim.x * blockDim.x) >> 6;
    const int zrow = n_nodes;            // zero row index in xb
    const int slast = E + 48;            // srcs over-read clamp (alloc has +64)

    float wv[DIM];
    #pragma unroll
    for (int k4 = 0; k4 < DIM / 4; ++k4) {
        float4 tw = *(const float4*)(W + (size_t)lane * DIM + k4 * 4);
        wv[k4 * 4 + 0] = tw.x; wv[k4 * 4 + 1] = tw.y;
        wv[k4 * 4 + 2] = tw.z; wv[k4 * 4 + 3] = tw.w;
    }
    const float bb = bias[lane];

    const int quads = (n_nodes + 3) >> 2;
    for (int q = gwave; q < quads; q += total_waves) {
        const int n0 = q << 2;
        int b0 = offsets[n0], e0 = offsets[n0 + 1];
        int b1 = 0, e1 = 0, b2 = 0, e2 = 0, b3 = 0, e3 = 0;
        if (n0 + 1 < n_nodes) { b1 = e0; e1 = offsets[n0 + 2]; }
        if (n0 + 2 < n_nodes) { b2 = e1; e2 = offsets[n0 + 3]; }
        if (n0 + 3 < n_nodes) { b3 = e2; e3 = offsets[n0 + 4]; }
        int c0 = (e0 - b0 + 7) >> 3, c1 = (e1 - b1 + 7) >> 3;
        int c2 = (e2 - b2 + 7) >> 3, c3 = (e3 - b3 + 7) >> 3;
        int cmax = max(max(c0, c1), max(c2, c3));
        cmax = __builtin_amdgcn_readfirstlane(cmax);

        float A0[8] = {0.f,0.f,0.f,0.f,0.f,0.f,0.f,0.f};
        float A1[8] = {0.f,0.f,0.f,0.f,0.f,0.f,0.f,0.f};
        float A2[8] = {0.f,0.f,0.f,0.f,0.f,0.f,0.f,0.f};
        float A3[8] = {0.f,0.f,0.f,0.f,0.f,0.f,0.f,0.f};

        for (int c = 0; c < cmax; ++c) {
            const int o = (c << 3) + sub;
            int i0 = b0 + o, i1 = b1 + o, i2 = b2 + o, i3 = b3 + o;
            // unconditional (possibly-garbage, in-bounds) reads
            int s0 = srcs[min(i0, slast)];
            int s1 = srcs[min(i1, slast)];
            int s2 = srcs[min(i2, slast)];
            int s3 = srcs[min(i3, slast)];
            // branchless validity: invalid slots -> zero row
            s0 = (i0 < e0) ? s0 : zrow;
            s1 = (i1 < e1) ? s1 : zrow;
            s2 = (i2 < e2) ? s2 : zrow;
            s3 = (i3 < e3) ? s3 : zrow;
            uint4 v0 = *(const uint4*)(xh + (size_t)s0 * DIM + fb);
            uint4 v1 = *(const uint4*)(xh + (size_t)s1 * DIM + fb);
            uint4 v2 = *(const uint4*)(xh + (size_t)s2 * DIM + fb);
            uint4 v3 = *(const uint4*)(xh + (size_t)s3 * DIM + fb);
            acc8(A0, v0); acc8(A1, v1); acc8(A2, v2); acc8(A3, v3);
        }

        #pragma unroll
        for (int d = 8; d <= 32; d <<= 1) {
            #pragma unroll
            for (int j = 0; j < 8; ++j) {
                A0[j] += __shfl_xor(A0[j], d, 64);
                A1[j] += __shfl_xor(A1[j], d, 64);
                A2[j] += __shfl_xor(A2[j], d, 64);
                A3[j] += __shfl_xor(A3[j], d, 64);
            }
        }

        out[(size_t)n0 * DIM + lane] = epilogue64(A0, wv, bb);
        if (n0 + 1 < n_nodes) out[(size_t)(n0 + 1) * DIM + lane] = epilogue64(A1, wv, bb);
        if (n0 + 2 < n_nodes) out[(size_t)(n0 + 2) * DIM + lane] = epilogue64(A2, wv, bb);
        if (n0 + 3 < n_nodes) out[(size_t)(n0 + 3) * DIM + lane] = epilogue64(A3, wv, bb);
    }
}

// ------------------- tier D: atomic scatter fallback -----------------------
__global__ void gcn_scatter_kernel(const float* __restrict__ x,
                                   const int* __restrict__ edge_index,
                                   float* __restrict__ out, int n_edges) {
    int gid = blockIdx.x * blockDim.x + threadIdx.x;
    int e = gid >> 4;
    if (e >= n_edges) return;
    int j = (gid & 15) << 2;
    int src = edge_index[e];
    int dst = edge_index[n_edges + e];
    const float4 v = *(const float4*)(x + (size_t)src * DIM + j);
    float* o = out + (size_t)dst * DIM + j;
    atomicAdd(o + 0, v.x); atomicAdd(o + 1, v.y);
    atomicAdd(o + 2, v.z); atomicAdd(o + 3, v.w);
}

__global__ void gcn_linear_inplace_kernel(float* __restrict__ out,
                                          const float* __restrict__ W,
                                          const float* __restrict__ bias,
                                          int n_nodes) {
    __shared__ float Wt[DIM * DIM];
    __shared__ float rows[4][DIM];
    int tid = threadIdx.x;
    int col = tid & 63;
    int r = tid >> 6;
    for (int i = tid; i < DIM * DIM; i += 256) {
        int c = i >> 6, k = i & 63;
        Wt[k * DIM + c] = W[i];
    }
    int row = blockIdx.x * 4 + r;
    if (row < n_nodes) rows[r][col] = out[(size_t)row * DIM + col];
    __syncthreads();
    if (row < n_nodes) {
        float a = 0.f;
        #pragma unroll
        for (int k = 0; k < DIM; ++k) a += rows[r][k] * Wt[k * DIM + col];
        out[(size_t)row * DIM + col] = a + bias[col];
    }
}

// ===========================================================================
extern "C" void kernel_launch(void* const* d_in, const int* in_sizes, int n_in,
                              void* d_out, int out_size, void* d_ws, size_t ws_size,
                              hipStream_t stream) {
    const float* x          = (const float*)d_in[0];   // [N, 64]
    const float* W          = (const float*)d_in[1];   // [64, 64]
    const float* bias       = (const float*)d_in[2];   // [64]
    const int*   edge_index = (const int*)d_in[3];     // [2, E] (int32)

    const int E = in_sizes[3] / 2;
    const int N = in_sizes[0] / DIM;
    float* out = (float*)d_out;

    const int nb = (N + BN - 1) >> BN_SHIFT;
    const long long M = (long long)nb * PBLK;
    const int block = 256;

    auto align256 = [](size_t v) { return (v + 255) & ~(size_t)255; };
    const size_t xb_b   = align256(((size_t)N + 1) * DIM * 2);   // +1 zero row
    const size_t bin_b  = align256((size_t)E * 4);
    const size_t hist_b = align256((size_t)M * 4);
    const size_t scan_b = align256(((size_t)M + 1) * 4);
    const size_t srcs_b = align256(((size_t)E + 64) * 4);        // +slack
    const size_t offs_b = align256(((size_t)N + 1) * 4);
    const size_t needA = xb_b + bin_b + hist_b + scan_b + srcs_b + offs_b;

    if (nb <= NB_MAX && ws_size >= needA) {
        char* p = (char*)d_ws;
        ushort4* xb4 = (ushort4*)p;          p += xb_b;
        int* binned  = (int*)p;              p += bin_b;
        int* bhistT  = (int*)p;              p += hist_b;
        int* scanT   = (int*)p;              p += scan_b;
        int* srcs    = (int*)p;              p += srcs_b;
        int* offsets = (int*)p;

        const int total4 = N * DIM / 4;

        convert_hist_kernel<<<PBLK, block, 0, stream>>>(
            x, edge_index, xb4, bhistT, E, N, nb, total4);
        scan_all_kernel<<<nb, block, 0, stream>>>(bhistT, scanT, nb);
        bin_scatter_kernel<<<PBLK, block, 0, stream>>>(
            edge_index, scanT, binned, E, nb);
        bucket_sort_kernel<<<nb, block, 0, stream>>>(
            binned, scanT, srcs, offsets, N, nb);

        const int quads = (N + 3) >> 2;
        const int gblocks = (quads + 7) / 8;     // ~2 quads per wave
        gather_quad_kernel<<<gblocks, block, 0, stream>>>(
            (const unsigned short*)xb4, offsets, srcs, W, bias, out, N, E);
    } else {
        hipMemsetAsync(d_out, 0, (size_t)out_size * sizeof(float), stream);
        long long total = (long long)E * 16;
        int grid = (int)((total + block - 1) / block);
        gcn_scatter_kernel<<<grid, block, 0, stream>>>(x, edge_index, out, E);
        int lgrid = (N + 3) / 4;
        gcn_linear_inplace_kernel<<<lgrid, 256, 0, stream>>>(out, W, bias, N);
    }
}